// Round 19
// baseline (267.610 us; speedup 1.0000x reference)
//
#include <hip/hip_runtime.h>
#include <hip/hip_bf16.h>

#define T_TOK 2048
#define H_DIM 1024
#define E_EXP 32
#define F_DIM 512
#define FS_DIM 1024
#define K_TOP 8
#define NGRP 8
#define TGRP 4
#define GSZ (E_EXP / NGRP)
#define RSCALE 2.5f
#define CAP 2048
#define NCVT_SLICE 8   // extra z-slices in GU dispatch for wd+sd conversion (many SHORT blocks)

typedef short  short8 __attribute__((ext_vector_type(8)));
typedef __bf16 bf16x4 __attribute__((ext_vector_type(4)));
typedef __bf16 bf16x8 __attribute__((ext_vector_type(8)));
typedef float  f32x4  __attribute__((ext_vector_type(4)));

// ---- shared cvt body: 8 floats/iter, 2x float4 load -> one 16B bf16x8 store (R14-proven) ----
__device__ __forceinline__ void cvt8_range(const float* __restrict__ s0, __bf16* __restrict__ d0, int n0,
                                           const float* __restrict__ s1, __bf16* __restrict__ d1, int n1,
                                           int base, int nthr) {
  const int ntot8 = (n0 + n1) >> 1;
  for (int gid = base; gid < ntot8; gid += nthr) {
    int t = gid << 1;                                   // float4 index (even)
    const float* src; __bf16* dst;
    if (t < n0) { src = s0; dst = d0; }
    else { t -= n0; src = s1; dst = d1; }
    const float4 va = reinterpret_cast<const float4*>(src)[t];
    const float4 vb = reinterpret_cast<const float4*>(src)[t + 1];
    bf16x8 o;
    o[0] = (__bf16)va.x; o[1] = (__bf16)va.y; o[2] = (__bf16)va.z; o[3] = (__bf16)va.w;
    o[4] = (__bf16)vb.x; o[5] = (__bf16)vb.y; o[6] = (__bf16)vb.z; o[7] = (__bf16)vb.w;
    *reinterpret_cast<bf16x8*>(reinterpret_cast<bf16x4*>(dst) + t) = o;  // 16B aligned (t even)
  }
}

// ================ prep: route (blocks 0..511, wave-per-token) ∥ cvt wgu+sgu ================
// Grid = 2560 > 2048 block capacity: the 512 extra cvt blocks QUEUE and backfill the
// CU slots the route blocks free at ~18us (R18 left those slots idle).
// Also zeroes counts[] (block NROUTE_BLK, lanes<32) -- scatter is the only consumer.
// NO atomics in route (R5: dependent per-wave atomicAdd -> 165 us).
#define NROUTE_BLK (T_TOK / 4)
__global__ __launch_bounds__(256) void prep_kernel(
    const float* __restrict__ x, const float* __restrict__ gw,
    const float* __restrict__ bias, int* __restrict__ tk_idx,
    float* __restrict__ tk_w, __bf16* __restrict__ xb,
    int* __restrict__ counts,
    const float* __restrict__ s0, __bf16* __restrict__ d0, int n0,   // wgu (float4 units)
    const float* __restrict__ s1, __bf16* __restrict__ d1, int n1) { // sgu
  if (blockIdx.x < NROUTE_BLK) {
    const int wid = threadIdx.x >> 6, lane = threadIdx.x & 63;
    const int t = blockIdx.x * 4 + wid;
    float xr[16];
#pragma unroll
    for (int i = 0; i < 16; i++) xr[i] = x[t * H_DIM + i * 64 + lane];
#pragma unroll
    for (int i = 0; i < 16; i++) xb[t * H_DIM + i * 64 + lane] = (__bf16)xr[i];
    float sc[E_EXP];
#pragma unroll
    for (int e = 0; e < E_EXP; e++) {
      const float* w = gw + e * H_DIM;
      float s = 0.f;
#pragma unroll
      for (int i = 0; i < 16; i++) s += xr[i] * w[i * 64 + lane];
#pragma unroll
      for (int off = 32; off > 0; off >>= 1) s += __shfl_xor(s, off);
      sc[e] = 1.f / (1.f + expf(-s));
    }
    if (lane == 0) {
      float b[E_EXP];
      for (int e = 0; e < E_EXP; e++) b[e] = sc[e] + bias[e];
      float gs[NGRP];
      for (int g = 0; g < NGRP; g++) {
        float m1 = -1e30f, m2 = -1e30f;
        for (int j = 0; j < GSZ; j++) {
          float v = b[g * GSZ + j];
          if (v > m1) { m2 = m1; m1 = v; } else if (v > m2) { m2 = v; }
        }
        gs[g] = m1 + m2;
      }
      unsigned gmask = 0;
      for (int it = 0; it < TGRP; it++) {
        float best = -1e30f; int bi = 0;
        for (int g = 0; g < NGRP; g++)
          if (!((gmask >> g) & 1) && gs[g] > best) { best = gs[g]; bi = g; }
        gmask |= 1u << bi;
      }
      unsigned emask = 0; float wsum = 0.f;
      int idx8[K_TOP];
      for (int it = 0; it < K_TOP; it++) {
        float best = -1e30f; int bi = 0;
        for (int e = 0; e < E_EXP; e++) {
          if (!((gmask >> (e / GSZ)) & 1)) continue;
          if ((emask >> e) & 1) continue;
          if (b[e] > best) { best = b[e]; bi = e; }
        }
        emask |= 1u << bi;
        idx8[it] = bi;
        wsum += sc[bi];
      }
      const float inv = 1.f / (wsum + 1e-20f);
      for (int k = 0; k < K_TOP; k++) {
        tk_idx[t * K_TOP + k] = idx8[k];
        tk_w[t * K_TOP + k] = sc[idx8[k]] * inv;
      }
    }
  } else {
    if (blockIdx.x == NROUTE_BLK && threadIdx.x < E_EXP) counts[threadIdx.x] = 0;
    const int nthr = (gridDim.x - NROUTE_BLK) * 256;
    const int base = (blockIdx.x - NROUTE_BLK) * 256 + threadIdx.x;
    cvt8_range(s0, d0, n0, s1, d1, n1, base, nthr);
  }
}

// ---------------- scatter: wave-parallel per-lane atomics ----------------
__global__ void scatter_kernel(const int* __restrict__ tk_idx, int* __restrict__ counts,
                               int* __restrict__ recs) {
  const int i = blockIdx.x * blockDim.x + threadIdx.x;
  if (i >= T_TOK * K_TOP) return;
  const int e = tk_idx[i];
  const int pos = atomicAdd(&counts[e], 1);
  recs[e * CAP + pos] = i;  // i == t*8 + k
}

// ---------------- fused grouped+shared GEMM (R6-proven m97 structure, 128x128, BK=64) ----------------
#define BM 128
#define BN 128
#define BK 64

__device__ __forceinline__ void gload_lds16(const void* g, void* l) {
  __builtin_amdgcn_global_load_lds(
      (__attribute__((address_space(1))) const void*)g,
      (__attribute__((address_space(3))) void*)l, 16, 0, 0);
}

// PHASE 0: z<32 -> GU expert z (A=xb gather, B=wgub, out=h_buf bf16 silu*up)
//          z in {32,33} -> shared GU slice s=z-32 (A=xb dense, B=sgub, out=hs)
//          z in [34, 34+NCVT_SLICE) -> SHORT cvt blocks for wd+sd (R16: +3us only)
// PHASE 1: z<32 -> DOWN expert z (A=h_buf slab, B=wdb, out=y_slot fp32 * tk_w)
//          z==32 -> shared DOWN (A=hs dense, B=sdb, out=d_out fp32)
template <int PHASE>
__global__ __launch_bounds__(256) void gemm_fused(
    const __bf16* __restrict__ Ar, const __bf16* __restrict__ As_,
    const __bf16* __restrict__ Br, const __bf16* __restrict__ Bs_,
    void* __restrict__ OutR, void* __restrict__ OutS,
    const int* __restrict__ recs, const int* __restrict__ counts,
    const float* __restrict__ tk_w,
    const float* __restrict__ cvt_s0, __bf16* __restrict__ cvt_d0, int cvt_n0,
    const float* __restrict__ cvt_s1, __bf16* __restrict__ cvt_d1, int cvt_n1) {

  const int z = blockIdx.z;

  if (PHASE == 0 && z >= E_EXP + 2) {
    // short ride-along cvt: 1024 blocks over wd+sd
    const int nblk = NCVT_SLICE * gridDim.x * gridDim.y;
    const int bid = (z - (E_EXP + 2)) * gridDim.x * gridDim.y + blockIdx.y * gridDim.x + blockIdx.x;
    cvt8_range(cvt_s0, cvt_d0, cvt_n0, cvt_s1, cvt_d1, cvt_n1, bid * 256 + threadIdx.x, nblk * 256);
    return;
  }

  const bool routed = (z < E_EXP);
  const int e = z;
  const int m0 = blockIdx.y * BM;
  const int bx = blockIdx.x;

  int count = T_TOK, off_e = 0;
  if (routed) {
    count = counts[e];
    for (int i = 0; i < E_EXP; i++) off_e += (i < e) ? counts[i] : 0;
    if (m0 >= count) return;   // block-uniform early exit, before any barrier
  }
  const int K = (PHASE == 0) ? H_DIM : (routed ? F_DIM : FS_DIM);

  const int tid = threadIdx.x, wid = tid >> 6, lane = tid & 63;

  __shared__ __align__(16) __bf16 Atile[BM * BK];
  __shared__ __align__(16) __bf16 Btile[BN * BK];

  const int colk = (lane & 7) * 8;
  const __bf16* aptr[4];
  const __bf16* bptr[4];
#pragma unroll
  for (int i = 0; i < 4; i++) {
    const int row = wid * 32 + i * 8 + (lane >> 3);
    int r = m0 + row; if (r > count - 1) r = count - 1;
    // ---- A source ----
    if (PHASE == 0) {
      if (routed) {
        const int rec = recs[e * CAP + r];
        aptr[i] = Ar + (size_t)(rec >> 3) * H_DIM + colk;     // gather token row of xb
      } else {
        aptr[i] = As_ + (size_t)r * H_DIM + colk;             // dense xb
      }
    } else {
      if (routed) aptr[i] = Ar + (size_t)(off_e + r) * F_DIM + colk;   // h slab
      else        aptr[i] = As_ + (size_t)r * FS_DIM + colk;           // hs dense
    }
    // ---- B source ----
    if (PHASE == 0) {
      if (routed) {
        const int brow = (row < 64) ? (bx * 64 + row) : (F_DIM + bx * 64 + row - 64);
        bptr[i] = Br + (size_t)e * 2 * F_DIM * H_DIM + (size_t)brow * H_DIM + colk;
      } else {
        const int s = z - E_EXP;
        const int fglob = s * 512 + bx * 64 + (row & 63);
        const int brow = (row < 64) ? fglob : (FS_DIM + fglob);
        bptr[i] = Bs_ + (size_t)brow * H_DIM + colk;
      }
    } else {
      if (routed) {
        const int brow = bx * BN + row;
        bptr[i] = Br + (size_t)e * H_DIM * F_DIM + (size_t)brow * F_DIM + colk;
      } else {
        const int brow = bx * BN + row;
        bptr[i] = Bs_ + (size_t)brow * FS_DIM + colk;
      }
    }
  }

  f32x4 acc[2][8];
#pragma unroll
  for (int a = 0; a < 2; a++)
#pragma unroll
    for (int b = 0; b < 8; b++) acc[a][b] = f32x4{0.f, 0.f, 0.f, 0.f};

  const int lr = lane & 15, lh = lane >> 4;

  for (int k0 = 0; k0 < K; k0 += BK) {
#pragma unroll
    for (int i = 0; i < 4; i++)
      gload_lds16(aptr[i] + k0, (char*)Atile + (wid * 4 + i) * 1024);
#pragma unroll
    for (int i = 0; i < 4; i++)
      gload_lds16(bptr[i] + k0, (char*)Btile + (wid * 4 + i) * 1024);
    __syncthreads();
#pragma unroll
    for (int kk = 0; kk < 2; kk++) {
      short8 af[2], bfr[8];
#pragma unroll
      for (int fm = 0; fm < 2; fm++)
        af[fm] = *reinterpret_cast<const short8*>(&Atile[(wid * 32 + fm * 16 + lr) * BK + kk * 32 + lh * 8]);
#pragma unroll
      for (int fn = 0; fn < 8; fn++)
        bfr[fn] = *reinterpret_cast<const short8*>(&Btile[(fn * 16 + lr) * BK + kk * 32 + lh * 8]);
#pragma unroll
      for (int fn = 0; fn < 8; fn++)
#pragma unroll
        for (int fm = 0; fm < 2; fm++)
          acc[fm][fn] = __builtin_amdgcn_mfma_f32_16x16x32_bf16(af[fm], bfr[fn], acc[fm][fn], 0, 0, 0);
    }
    __syncthreads();
  }

  // ---------------- epilogues ----------------
  if (PHASE == 0) {
    // silu(gate) * up -> bf16
#pragma unroll
    for (int fm = 0; fm < 2; fm++)
#pragma unroll
      for (int j = 0; j < 4; j++) {
        const int row = wid * 32 + fm * 16 + lh * 4 + j;
        if (m0 + row < count) {
#pragma unroll
          for (int fn = 0; fn < 4; fn++) {
            const float g = acc[fm][fn][j], u = acc[fm][fn + 4][j];
            const float hv = g / (1.f + expf(-g)) * u;
            if (routed) {
              const int f = bx * 64 + fn * 16 + lr;
              ((__bf16*)OutR)[(size_t)(off_e + m0 + row) * F_DIM + f] = (__bf16)hv;
            } else {
              const int s = z - E_EXP;
              const int f = s * 512 + bx * 64 + fn * 16 + lr;
              ((__bf16*)OutS)[(size_t)(m0 + row) * FS_DIM + f] = (__bf16)hv;
            }
          }
        }
      }
  } else {
#pragma unroll
    for (int fm = 0; fm < 2; fm++)
#pragma unroll
      for (int j = 0; j < 4; j++) {
        const int row = wid * 32 + fm * 16 + lh * 4 + j;
        if (m0 + row < count) {
          if (routed) {
            const int rec = recs[e * CAP + m0 + row];   // == t*8+k, the y_slot row
            const float w = tk_w[rec];
            const size_t base = (size_t)rec * H_DIM + bx * BN;
#pragma unroll
            for (int fn = 0; fn < 8; fn++)
              ((float*)OutR)[base + fn * 16 + lr] = acc[fm][fn][j] * w;
          } else {
#pragma unroll
            for (int fn = 0; fn < 8; fn++)
              ((float*)OutS)[(size_t)(m0 + row) * H_DIM + bx * BN + fn * 16 + lr] = acc[fm][fn][j];
          }
        }
      }
  }
}

// ---------------- combine: out = shared + SCALE * sum_k y_slot[t,k] ----------------
__global__ void combine_kernel(const float* __restrict__ y_slot, float* __restrict__ out) {
  const int gid = blockIdx.x * blockDim.x + threadIdx.x;
  const int t = gid >> 8;
  const int c0 = (gid & 255) * 4;
  float4 s = {0.f, 0.f, 0.f, 0.f};
#pragma unroll
  for (int k = 0; k < K_TOP; k++) {
    const float4 v = *reinterpret_cast<const float4*>(&y_slot[((size_t)t * K_TOP + k) * H_DIM + c0]);
    s.x += v.x; s.y += v.y; s.z += v.z; s.w += v.w;
  }
  float4 o = *reinterpret_cast<float4*>(&out[(size_t)t * H_DIM + c0]);
  o.x += RSCALE * s.x; o.y += RSCALE * s.y; o.z += RSCALE * s.z; o.w += RSCALE * s.w;
  *reinterpret_cast<float4*>(&out[(size_t)t * H_DIM + c0]) = o;
}

// ---------------- launch ----------------
extern "C" void kernel_launch(void* const* d_in, const int* in_sizes, int n_in,
                              void* d_out, int out_size, void* d_ws, size_t ws_size,
                              hipStream_t stream) {
  const float* x    = (const float*)d_in[0];
  const float* gw   = (const float*)d_in[1];
  const float* bias = (const float*)d_in[2];
  const float* wgu  = (const float*)d_in[3];
  const float* wd   = (const float*)d_in[4];
  const float* sgu  = (const float*)d_in[5];
  const float* sd   = (const float*)d_in[6];

  char* ws = (char*)d_ws;
  size_t o = 0;
  auto alloc = [&](size_t bytes) {
    char* p = ws + o;
    o += (bytes + 255) & ~(size_t)255;
    return (void*)p;
  };
  __bf16* xb     = (__bf16*)alloc((size_t)T_TOK * H_DIM * 2);
  __bf16* wgub   = (__bf16*)alloc((size_t)E_EXP * 2 * F_DIM * H_DIM * 2);
  __bf16* wdb    = (__bf16*)alloc((size_t)E_EXP * H_DIM * F_DIM * 2);
  __bf16* sgub   = (__bf16*)alloc((size_t)2 * FS_DIM * H_DIM * 2);
  __bf16* sdb    = (__bf16*)alloc((size_t)H_DIM * FS_DIM * 2);
  __bf16* h_buf  = (__bf16*)alloc((size_t)T_TOK * K_TOP * F_DIM * 2);
  float*  y_slot = (float*) alloc((size_t)T_TOK * K_TOP * H_DIM * 4);
  __bf16* hs     = (__bf16*)alloc((size_t)T_TOK * FS_DIM * 2);
  int*   tk_idx  = (int*)  alloc((size_t)T_TOK * K_TOP * 4);
  float* tk_w    = (float*)alloc((size_t)T_TOK * K_TOP * 4);
  int*   counts  = (int*)  alloc((size_t)E_EXP * 4);
  int*   recs    = (int*)  alloc((size_t)E_EXP * CAP * 4);
  if (o > ws_size) return;

  // 1. prep: route + xb (blocks 0..511) ∥ cvt wgu+sgu (blocks 512..2559, 512 queued
  //    to backfill slots freed when route retires); zeroes counts
  prep_kernel<<<2560, 256, 0, stream>>>(
      x, gw, bias, tk_idx, tk_w, xb, counts,
      wgu, wgub, E_EXP * 2 * F_DIM * H_DIM / 4,
      sgu, sgub, 2 * FS_DIM * H_DIM / 4);

  // 2. scatter (wave-parallel atomics)
  scatter_kernel<<<(T_TOK * K_TOP + 255) / 256, 256, 0, stream>>>(tk_idx, counts, recs);

  // 3. gate_up (routed z<32, shared z=32,33) + SHORT wd/sd cvt slices (z=34..41)
  gemm_fused<0><<<dim3(F_DIM / 64, T_TOK / BM, E_EXP + 2 + NCVT_SLICE), 256, 0, stream>>>(
      xb, xb, wgub, sgub, h_buf, hs, recs, counts, tk_w,
      wd, wdb, E_EXP * H_DIM * F_DIM / 4, sd, sdb, H_DIM * FS_DIM / 4);

  // 4. down (routed z<32, shared z=32)
  gemm_fused<1><<<dim3(H_DIM / BN, T_TOK / BM, E_EXP + 1), 256, 0, stream>>>(
      h_buf, hs, wdb, sdb, y_slot, d_out, recs, counts, tk_w,
      (const float*)nullptr, (__bf16*)nullptr, 0, (const float*)nullptr, (__bf16*)nullptr, 0);

  // 5. combine
  combine_kernel<<<T_TOK * H_DIM / 4 / 256, 256, 0, stream>>>(y_slot, (float*)d_out);
}